// Round 1
// baseline (624.585 us; speedup 1.0000x reference)
//
#include <hip/hip_runtime.h>
#include <hip/hip_bf16.h>

// ---------------------------------------------------------------------------
// DeepCut fused pipeline, fp32. B=4, T=4096 (64x64), D=384, K=8, CH=64, NL=4.
// Graph = 5x5 box stencil with separable D^-1/2 normalization u(i)*u(j).
// ---------------------------------------------------------------------------

#define B_ 4
#define T_ 4096
#define D_ 384
#define K_ 8
#define CH_ 64

__device__ __forceinline__ float wred(float v) {
#pragma unroll
  for (int off = 32; off > 0; off >>= 1) v += __shfl_xor(v, off);
  return v;
}

// u(i) = rsqrt(#valid offsets in [-2,2] along one axis)
__device__ __forceinline__ float uval(int i) {
  int c = (i < 2 ? i : 2) + ((63 - i) < 2 ? (63 - i) : 2) + 1;
  return rsqrtf((float)c);
}

// ---- zero the accumulator block (512 floats) ----
__global__ void k_zero(float* __restrict__ acc) {
  acc[threadIdx.x] = 0.f;
  acc[threadIdx.x + 256] = 0.f;
}

// ---- transpose ec_w1 (32,384,3,3) -> wT[q][d][o], q=ky*3+kx ----
__global__ void k_wT(const float* __restrict__ w, float* __restrict__ wT) {
  int idx = blockIdx.x * 256 + threadIdx.x;
  if (idx >= 32 * 384 * 9) return;
  int q = idx % 9;
  int rest = idx / 9;
  int d = rest % 384;
  int o = rest / 384;
  wT[q * 12288 + d * 32 + o] = w[idx];
}

// ---- layer-0 GEMM: xw = [feat,pos]@W0 ; res = LN([feat,pos]@res_w + res_b) ----
__global__ __launch_bounds__(256) void k_gemm0(
    const float* __restrict__ feat, const float* __restrict__ w0,
    const float* __restrict__ resw, const float* __restrict__ resb,
    const float* __restrict__ resg, const float* __restrict__ reslb,
    float* __restrict__ xw, float* __restrict__ res) {
  __shared__ float sf[4 * 384];
  int row0 = blockIdx.x * 4;
  const float4* f4 = (const float4*)(feat + (size_t)row0 * D_);
  float4* sf4 = (float4*)sf;
  for (int i = threadIdx.x; i < 384; i += 256) sf4[i] = f4[i];
  __syncthreads();
  int r = threadIdx.x >> 6, c = threadIdx.x & 63;
  int row = row0 + r;
  int t = row & (T_ - 1);
  float px = (float)(t & 63) * (1.0f / 63.0f);
  float py = (float)(t >> 6) * (1.0f / 63.0f);
  float a1 = 0.f, a2 = 0.f;
  const float* sfr = sf + r * D_;
#pragma unroll 4
  for (int k = 0; k < D_; ++k) {
    float fv = sfr[k];
    a1 = fmaf(fv, w0[k * 64 + c], a1);
    a2 = fmaf(fv, resw[k * 64 + c], a2);
  }
  a1 += px * w0[384 * 64 + c] + py * w0[385 * 64 + c];
  a2 += px * resw[384 * 64 + c] + py * resw[385 * 64 + c] + resb[c];
  xw[(size_t)row * 64 + c] = a1;
  // LayerNorm over 64 channels (one wave = one row)
  float m = wred(a2) * (1.f / 64.f);
  float d = a2 - m;
  float v = wred(d * d) * (1.f / 64.f);
  res[(size_t)row * 64 + c] = d * rsqrtf(v + 1e-5f) * resg[c] + reslb[c];
}

// ---- generic 64->64 GEMM (no bias): Y = X@W ----
__global__ __launch_bounds__(256) void k_gemm64(const float* __restrict__ X,
                                                const float* __restrict__ W,
                                                float* __restrict__ Y) {
  __shared__ float sf[256];
  size_t base = (size_t)blockIdx.x * 256;
  sf[threadIdx.x] = X[base + threadIdx.x];
  __syncthreads();
  int r = threadIdx.x >> 6, c = threadIdx.x & 63;
  float a = 0.f;
  const float* sfr = sf + r * 64;
#pragma unroll
  for (int k = 0; k < 64; ++k) a = fmaf(sfr[k], W[k * 64 + c], a);
  Y[base + threadIdx.x] = a;
}

// ---- stencil + bias + LN + ELU + residual: xout = elu(LN(A@xw + b)) + resid ----
__global__ __launch_bounds__(256) void k_stencil(
    const float* __restrict__ xw, const float* __restrict__ bias,
    const float* __restrict__ lng, const float* __restrict__ lnb,
    const float* __restrict__ resid, float* __restrict__ xout) {
  int r = threadIdx.x >> 6, c = threadIdx.x & 63;
  int row = blockIdx.x * 4 + r;
  int b = row >> 12, t = row & (T_ - 1);
  int i = t >> 6, j = t & 63;
  float ui = uval(i), uj = uval(j);
  float s = 0.f;
#pragma unroll
  for (int di = -2; di <= 2; ++di) {
    int ii = i + di;
    if (ii < 0 || ii > 63) continue;
    float wi = uval(ii);
#pragma unroll
    for (int dj = -2; dj <= 2; ++dj) {
      int jj = j + dj;
      if (jj < 0 || jj > 63) continue;
      s = fmaf(wi * uval(jj), xw[((size_t)((b << 12) + (ii << 6) + jj)) * 64 + c], s);
    }
  }
  float h = ui * uj * s + bias[c];
  float m = wred(h) * (1.f / 64.f);
  float d = h - m;
  float v = wred(d * d) * (1.f / 64.f);
  float n = d * rsqrtf(v + 1e-5f) * lng[c] + lnb[c];
  float e = n > 0.f ? n : (expf(n) - 1.f);
  xout[(size_t)row * 64 + c] = e + resid[(size_t)row * 64 + c];
}

// ---- MLP head: h1 = elu(LN(x@w1+b1)); S = softmax(h1@w2+b2) ----
__global__ __launch_bounds__(256) void k_mlp(
    const float* __restrict__ X, const float* __restrict__ w1,
    const float* __restrict__ b1, const float* __restrict__ lng,
    const float* __restrict__ lnb, const float* __restrict__ w2,
    const float* __restrict__ b2, float* __restrict__ S) {
  int r = threadIdx.x >> 6, lane = threadIdx.x & 63;
  size_t row = (size_t)blockIdx.x * 4 + r;
  float xv = X[row * 64 + lane];
  float a = b1[lane];
#pragma unroll
  for (int k = 0; k < 64; ++k) {
    float xk = __shfl(xv, k);
    a = fmaf(xk, w1[k * 64 + lane], a);
  }
  float m = wred(a) * (1.f / 64.f);
  float d = a - m;
  float v = wred(d * d) * (1.f / 64.f);
  float h = d * rsqrtf(v + 1e-5f) * lng[lane] + lnb[lane];
  h = h > 0.f ? h : (expf(h) - 1.f);
  float lg0 = wred(h * w2[lane * 8 + 0]) + b2[0];
  float lg1 = wred(h * w2[lane * 8 + 1]) + b2[1];
  float lg2 = wred(h * w2[lane * 8 + 2]) + b2[2];
  float lg3 = wred(h * w2[lane * 8 + 3]) + b2[3];
  float lg4 = wred(h * w2[lane * 8 + 4]) + b2[4];
  float lg5 = wred(h * w2[lane * 8 + 5]) + b2[5];
  float lg6 = wred(h * w2[lane * 8 + 6]) + b2[6];
  float lg7 = wred(h * w2[lane * 8 + 7]) + b2[7];
  float mx = fmaxf(fmaxf(fmaxf(lg0, lg1), fmaxf(lg2, lg3)),
                   fmaxf(fmaxf(lg4, lg5), fmaxf(lg6, lg7)));
  lg0 = expf(lg0 - mx); lg1 = expf(lg1 - mx); lg2 = expf(lg2 - mx);
  lg3 = expf(lg3 - mx); lg4 = expf(lg4 - mx); lg5 = expf(lg5 - mx);
  lg6 = expf(lg6 - mx); lg7 = expf(lg7 - mx);
  float inv = 1.f / (lg0 + lg1 + lg2 + lg3 + lg4 + lg5 + lg6 + lg7);
  if (lane < 8) {
    float val = lane == 0 ? lg0 : lane == 1 ? lg1 : lane == 2 ? lg2 :
                lane == 3 ? lg3 : lane == 4 ? lg4 : lane == 5 ? lg5 :
                lane == 6 ? lg6 : lg7;
    S[row * 8 + lane] = val * inv;
  }
}

// ---- transpose S (B,T,K) -> Sp (B,K,T) ----
__global__ void k_transS(const float* __restrict__ S, float* __restrict__ Sp) {
  int idx = blockIdx.x * 256 + threadIdx.x;  // (b*8+k)*4096 + t
  int t = idx & (T_ - 1);
  int bk = idx >> 12;
  int k = bk & 7, b = bk >> 3;
  Sp[idx] = S[((size_t)((b << 12) + t)) * 8 + k];
}

// ---- normalized-cut num/den: AS = A@S ; num=S.AS ; den=S^2*degA ----
__global__ __launch_bounds__(256) void k_cut(const float* __restrict__ S,
                                             float* __restrict__ acc) {
  int k = threadIdx.x & 7;
  int tl = threadIdx.x >> 3;
  int gid = blockIdx.x * 32 + tl;
  int b = gid >> 12, t = gid & (T_ - 1);
  int i = t >> 6, j = t & 63;
  float ui = uval(i), uj = uval(j);
  float as = 0.f, sui = 0.f, suj = 0.f;
#pragma unroll
  for (int di = -2; di <= 2; ++di) {
    int ii = i + di;
    if (ii < 0 || ii > 63) continue;
    float wi = uval(ii);
    sui += wi;
#pragma unroll
    for (int dj = -2; dj <= 2; ++dj) {
      int jj = j + dj;
      if (jj < 0 || jj > 63) continue;
      as = fmaf(wi * uval(jj), S[((size_t)((b << 12) + (ii << 6) + jj)) * 8 + k], as);
    }
  }
#pragma unroll
  for (int dj = -2; dj <= 2; ++dj) {
    int jj = j + dj;
    if (jj >= 0 && jj <= 63) suj += uval(jj);
  }
  as *= ui * uj;
  float sv = S[(size_t)gid * 8 + k];
  float degA = ui * uj * sui * suj;
  float numv = wred(sv * as);
  float denv = wred(sv * sv * degA);
  __shared__ float lds[8];
  int wid = threadIdx.x >> 6, lane = threadIdx.x & 63;
  if (lane == 0) { lds[wid * 2] = numv; lds[wid * 2 + 1] = denv; }
  __syncthreads();
  if (threadIdx.x == 0) {
    atomicAdd(&acc[0 + b], lds[0] + lds[2] + lds[4] + lds[6]);
    atomicAdd(&acc[4 + b], lds[1] + lds[3] + lds[5] + lds[7]);
  }
}

// ---- SS[b,k,l] = sum_t S[t,k]S[t,l] ----
__global__ __launch_bounds__(256) void k_SS(const float* __restrict__ S,
                                            float* __restrict__ acc) {
  int bk = blockIdx.x;      // 32 blocks: b*8 + chunk
  int b = bk >> 3, chunk = bk & 7;
  int wid = threadIdx.x >> 6, lane = threadIdx.x & 63;
  int kk = lane >> 3, ll = lane & 7;
  int t0 = chunk * 512 + wid * 128;
  float a = 0.f;
  const float* Sb = S + ((size_t)b << 12) * 8;
  for (int it = 0; it < 128; ++it) {
    const float* sr = Sb + (size_t)(t0 + it) * 8;
    a = fmaf(sr[kk], sr[ll], a);
  }
  __shared__ float lds[256];
  lds[threadIdx.x] = a;
  __syncthreads();
  if (threadIdx.x < 64) {
    float s = lds[threadIdx.x] + lds[threadIdx.x + 64] + lds[threadIdx.x + 128] +
              lds[threadIdx.x + 192];
    atomicAdd(&acc[80 + b * 64 + threadIdx.x], s);
  }
}

// ---- spatial smoothness: per (b,k) plane, 2x depthwise conv3x3 + per-plane GN ----
__global__ __launch_bounds__(256) void k_sm(
    const float* __restrict__ Sp, const float* __restrict__ w1,
    const float* __restrict__ b1, const float* __restrict__ g1,
    const float* __restrict__ bb1, const float* __restrict__ w2,
    const float* __restrict__ b2, const float* __restrict__ g2,
    const float* __restrict__ bb2, float* __restrict__ acc) {
  __shared__ float p0[4096];
  __shared__ float p1[4096];
  __shared__ float red[8];
  int bk = blockIdx.x, b = bk >> 3, k = bk & 7;
  const float4* src = (const float4*)(Sp + (size_t)bk * 4096);
  float4* d0 = (float4*)p0;
  for (int i = threadIdx.x; i < 1024; i += 256) d0[i] = src[i];
  float W1[9], W2[9];
#pragma unroll
  for (int q = 0; q < 9; ++q) { W1[q] = w1[k * 9 + q]; W2[q] = w2[k * 9 + q]; }
  __syncthreads();
  int wid = threadIdx.x >> 6, lane = threadIdx.x & 63;
  float y[16];
  float s1 = 0.f, s2 = 0.f;
#pragma unroll
  for (int v = 0; v < 16; ++v) {
    int p = v * 256 + threadIdx.x;
    int i = p >> 6, j = p & 63;
    float a = b1[k];
#pragma unroll
    for (int dy = 0; dy < 3; ++dy) {
      int ii = i + dy - 1;
      if (ii < 0 || ii > 63) continue;
#pragma unroll
      for (int dx = 0; dx < 3; ++dx) {
        int jj = j + dx - 1;
        if (jj < 0 || jj > 63) continue;
        a = fmaf(W1[dy * 3 + dx], p0[(ii << 6) + jj], a);
      }
    }
    y[v] = a;
    s1 += a;
    s2 = fmaf(a, a, s2);
  }
  s1 = wred(s1); s2 = wred(s2);
  if (lane == 0) { red[wid * 2] = s1; red[wid * 2 + 1] = s2; }
  __syncthreads();
  float mean = (red[0] + red[2] + red[4] + red[6]) * (1.f / 4096.f);
  float var = (red[1] + red[3] + red[5] + red[7]) * (1.f / 4096.f) - mean * mean;
  float inv = rsqrtf(var + 1e-5f) * g1[k];
  float sh = bb1[k];
  __syncthreads();
#pragma unroll
  for (int v = 0; v < 16; ++v) {
    int p = v * 256 + threadIdx.x;
    p1[p] = fmaxf((y[v] - mean) * inv + sh, 0.f);
  }
  __syncthreads();
  s1 = 0.f; s2 = 0.f;
#pragma unroll
  for (int v = 0; v < 16; ++v) {
    int p = v * 256 + threadIdx.x;
    int i = p >> 6, j = p & 63;
    float a = b2[k];
#pragma unroll
    for (int dy = 0; dy < 3; ++dy) {
      int ii = i + dy - 1;
      if (ii < 0 || ii > 63) continue;
#pragma unroll
      for (int dx = 0; dx < 3; ++dx) {
        int jj = j + dx - 1;
        if (jj < 0 || jj > 63) continue;
        a = fmaf(W2[dy * 3 + dx], p1[(ii << 6) + jj], a);
      }
    }
    y[v] = a;
    s1 += a;
    s2 = fmaf(a, a, s2);
  }
  s1 = wred(s1); s2 = wred(s2);
  if (lane == 0) { red[wid * 2] = s1; red[wid * 2 + 1] = s2; }
  __syncthreads();
  float mean2 = (red[0] + red[2] + red[4] + red[6]) * (1.f / 4096.f);
  float var2 = (red[1] + red[3] + red[5] + red[7]) * (1.f / 4096.f) - mean2 * mean2;
  float inv2 = rsqrtf(var2 + 1e-5f) * g2[k];
  float sh2 = bb2[k];
  float sd = 0.f;
#pragma unroll
  for (int v = 0; v < 16; ++v) {
    int p = v * 256 + threadIdx.x;
    float sm = (y[v] - mean2) * inv2 + sh2;
    float dd = sm - p0[p];
    sd = fmaf(dd, dd, sd);
  }
  sd = wred(sd);
  __syncthreads();
  if (lane == 0) red[wid] = sd;
  __syncthreads();
  if (threadIdx.x == 0)
    atomicAdd(&acc[8 + b], (red[0] + red[1] + red[2] + red[3]) * (1.f / 32768.f));
}

// ---- edge conv: e_raw = conv3x3(feat(B,384,H,W) as NHWC rows) -> (B,32,H,W) ----
__global__ __launch_bounds__(256) void k_ecconv(
    const float* __restrict__ feat, const float* __restrict__ wT,
    const float* __restrict__ b1, float* __restrict__ eraw,
    float* __restrict__ acc) {
  __shared__ float sf[11520];  // 3 rows x 10 cols x 384
  __shared__ float sstat[16];
  int blk = blockIdx.x;
  int b = blk >> 9;
  int rem = blk & 511;
  int i = rem >> 3;
  int j0 = (rem & 7) << 3;
  if (threadIdx.x < 16) sstat[threadIdx.x] = 0.f;
  float4* sf4 = (float4*)sf;
  for (int l = threadIdx.x; l < 2880; l += 256) {
    int s = l / 96, v = l - s * 96;
    int r = s / 10, cc = s - r * 10;
    int is = i + r - 1, js = j0 + cc - 1;
    float4 val = make_float4(0.f, 0.f, 0.f, 0.f);
    if (is >= 0 && is < 64 && js >= 0 && js < 64)
      val = ((const float4*)(feat + ((size_t)((b << 12) + (is << 6) + js)) * D_))[v];
    sf4[l] = val;
  }
  __syncthreads();
  int p = threadIdx.x >> 5, o = threadIdx.x & 31;
  float a = 0.f;
#pragma unroll
  for (int r = 0; r < 3; ++r) {
#pragma unroll
    for (int dj = 0; dj < 3; ++dj) {
      const float* fp = sf + (r * 10 + p + dj) * D_;
      const float* wp = wT + (r * 3 + dj) * 12288 + o;
#pragma unroll 8
      for (int d = 0; d < D_; ++d) a = fmaf(fp[d], wp[d << 5], a);
    }
  }
  a += b1[o];
  eraw[((size_t)(b * 32 + o) << 12) + (i << 6) + j0 + p] = a;
  int g = o >> 2;
  atomicAdd(&sstat[g * 2], a);
  atomicAdd(&sstat[g * 2 + 1], a * a);
  __syncthreads();
  if (threadIdx.x < 16) atomicAdd(&acc[16 + b * 16 + threadIdx.x], sstat[threadIdx.x]);
}

// ---- GN + relu + 1x1 conv + sigmoid -> ew (B,T) ----
__global__ __launch_bounds__(256) void k_ecfinal(
    const float* __restrict__ eraw, const float* __restrict__ acc,
    const float* __restrict__ gng, const float* __restrict__ gnb,
    const float* __restrict__ w2, const float* __restrict__ b2,
    float* __restrict__ ew) {
  __shared__ float st[16];
  int idx = blockIdx.x * 256 + threadIdx.x;
  int b = idx >> 12, pix = idx & (T_ - 1);
  if (threadIdx.x < 16) st[threadIdx.x] = acc[16 + b * 16 + threadIdx.x];
  __syncthreads();
  float a = b2[0];
#pragma unroll 8
  for (int o = 0; o < 32; ++o) {
    int g = o >> 2;
    float mean = st[g * 2] * (1.f / 16384.f);
    float var = st[g * 2 + 1] * (1.f / 16384.f) - mean * mean;
    float e = eraw[((size_t)(b * 32 + o) << 12) + pix];
    e = (e - mean) * rsqrtf(var + 1e-5f) * gng[o] + gnb[o];
    a = fmaf(fmaxf(e, 0.f), w2[o], a);
  }
  ew[idx] = 1.f / (1.f + expf(-a));
}

// ---- feature-smoothness gradient sums ----
__global__ __launch_bounds__(256) void k_fsloss(const float* __restrict__ feat,
                                                const float* __restrict__ ew,
                                                float* __restrict__ acc) {
  float sy = 0.f, sx = 0.f;
  const int N = B_ * T_ * 96;
  for (int idx = blockIdx.x * 256 + threadIdx.x; idx < N; idx += gridDim.x * 256) {
    int d4 = idx % 96;
    int rt = idx / 96;
    int t = rt & (T_ - 1);
    int i = t >> 6, j = t & 63;
    const float4* fp = (const float4*)(feat + (size_t)rt * D_) + d4;
    float4 f0 = *fp;
    if (i < 63) {
      float4 f1 = fp[64 * 96];
      float w = ew[rt + 64];
      float a = f1.x - f0.x, bq = f1.y - f0.y, c = f1.z - f0.z, d = f1.w - f0.w;
      sy += w * (a * a + bq * bq + c * c + d * d);
    }
    if (j < 63) {
      float4 f1 = fp[96];
      float w = ew[rt + 1];
      float a = f1.x - f0.x, bq = f1.y - f0.y, c = f1.z - f0.z, d = f1.w - f0.w;
      sx += w * (a * a + bq * bq + c * c + d * d);
    }
  }
  sy = wred(sy);
  sx = wred(sx);
  __shared__ float lds[8];
  int wid = threadIdx.x >> 6, lane = threadIdx.x & 63;
  if (lane == 0) { lds[wid * 2] = sy; lds[wid * 2 + 1] = sx; }
  __syncthreads();
  if (threadIdx.x == 0) {
    atomicAdd(&acc[12], lds[0] + lds[2] + lds[4] + lds[6]);
    atomicAdd(&acc[13], lds[1] + lds[3] + lds[5] + lds[7]);
  }
}

// ---- final scalar assembly ----
__global__ void k_final(const float* __restrict__ acc, float* __restrict__ out) {
  if (threadIdx.x != 0 || blockIdx.x != 0) return;
  float total = 0.f;
  for (int b = 0; b < 4; ++b) {
    const float* SSb = acc + 80 + b * 64;
    float ssq = 0.f;
    for (int v = 0; v < 64; ++v) ssq += SSb[v] * SSb[v];
    float ssn = sqrtf(ssq);
    float tgt = 1.f / (sqrtf(8.f) + 1e-6f);
    float inv = 1.f / (ssn + 1e-6f);
    float lo = 0.f;
    for (int kk = 0; kk < 8; ++kk)
      for (int ll = 0; ll < 8; ++ll) {
        float dd = SSb[kk * 8 + ll] * inv - (kk == ll ? tgt : 0.f);
        lo += dd * dd;
      }
    lo = sqrtf(lo);
    float lc = -acc[b] / (acc[4 + b] + 1e-6f);
    total += lc + lo + 0.01f * acc[8 + b];
  }
  total *= 0.25f;
  const float cnt = 4.f * 384.f * 63.f * 64.f;
  float ly = acc[12] / cnt * (1.f / 384.f);
  float lx = acc[13] / cnt * (1.f / 384.f);
  out[131072] = total + 0.09f * 0.5f * (ly + lx);
}

extern "C" void kernel_launch(void* const* d_in, const int* in_sizes, int n_in,
                              void* d_out, int out_size, void* d_ws, size_t ws_size,
                              hipStream_t stream) {
  const float* feat = (const float*)d_in[0];
  const float* gcn_w0 = (const float*)d_in[1];
  const float* gcn_b0 = (const float*)d_in[2];
  const float* gcn_w = (const float*)d_in[3];
  const float* gcn_b = (const float*)d_in[4];
  const float* ln_g = (const float*)d_in[5];
  const float* ln_b = (const float*)d_in[6];
  const float* res_w = (const float*)d_in[7];
  const float* res_b = (const float*)d_in[8];
  const float* res_ln_g = (const float*)d_in[9];
  const float* res_ln_b = (const float*)d_in[10];
  const float* mlp_w1 = (const float*)d_in[11];
  const float* mlp_b1 = (const float*)d_in[12];
  const float* mlp_ln_g = (const float*)d_in[13];
  const float* mlp_ln_b = (const float*)d_in[14];
  const float* mlp_w2 = (const float*)d_in[15];
  const float* mlp_b2 = (const float*)d_in[16];
  const float* sm_w1 = (const float*)d_in[17];
  const float* sm_b1 = (const float*)d_in[18];
  const float* sm_g1 = (const float*)d_in[19];
  const float* sm_bb1 = (const float*)d_in[20];
  const float* sm_w2 = (const float*)d_in[21];
  const float* sm_b2 = (const float*)d_in[22];
  const float* sm_g2 = (const float*)d_in[23];
  const float* sm_bb2 = (const float*)d_in[24];
  const float* ec_w1 = (const float*)d_in[25];
  const float* ec_b1 = (const float*)d_in[26];
  const float* ec_gn_g = (const float*)d_in[27];
  const float* ec_gn_b = (const float*)d_in[28];
  const float* ec_w2 = (const float*)d_in[29];
  const float* ec_b2 = (const float*)d_in[30];

  float* out = (float*)d_out;
  float* ws = (float*)d_ws;
  float* acc = ws;                       // 512 floats
  float* xw = ws + 512;                  // B*T*64
  float* xbuf = xw + 1048576;            // B*T*64
  float* resbuf = xbuf + 1048576;        // B*T*64
  float* Sp = resbuf + 1048576;          // B*K*T
  float* eraw = Sp + 131072;             // B*32*T
  float* ew = eraw + 524288;             // B*T
  float* wT = ew + 16384;                // 110592
  float* S = out;                        // (B,T,K) straight into d_out

  k_zero<<<1, 256, 0, stream>>>(acc);
  k_wT<<<(110592 + 255) / 256, 256, 0, stream>>>(ec_w1, wT);

  k_gemm0<<<B_ * T_ / 4, 256, 0, stream>>>(feat, gcn_w0, res_w, res_b, res_ln_g,
                                           res_ln_b, xw, resbuf);
  k_stencil<<<B_ * T_ / 4, 256, 0, stream>>>(xw, gcn_b0, ln_g, ln_b, resbuf, xbuf);
  for (int i = 1; i < 4; ++i) {
    k_gemm64<<<B_ * T_ / 4, 256, 0, stream>>>(xbuf, gcn_w + (i - 1) * 4096, xw);
    k_stencil<<<B_ * T_ / 4, 256, 0, stream>>>(xw, gcn_b + (i - 1) * 64,
                                               ln_g + i * 64, ln_b + i * 64, xbuf,
                                               xbuf);
  }
  k_mlp<<<B_ * T_ / 4, 256, 0, stream>>>(xbuf, mlp_w1, mlp_b1, mlp_ln_g, mlp_ln_b,
                                         mlp_w2, mlp_b2, S);

  k_transS<<<B_ * K_ * T_ / 256, 256, 0, stream>>>(S, Sp);
  k_cut<<<B_ * T_ / 32, 256, 0, stream>>>(S, acc);
  k_SS<<<32, 256, 0, stream>>>(S, acc);
  k_sm<<<32, 256, 0, stream>>>(Sp, sm_w1, sm_b1, sm_g1, sm_bb1, sm_w2, sm_b2, sm_g2,
                               sm_bb2, acc);

  k_ecconv<<<2048, 256, 0, stream>>>(feat, wT, ec_b1, eraw, acc);
  k_ecfinal<<<B_ * T_ / 256, 256, 0, stream>>>(eraw, acc, ec_gn_g, ec_gn_b, ec_w2,
                                               ec_b2, ew);
  k_fsloss<<<2048, 256, 0, stream>>>(feat, ew, acc);
  k_final<<<1, 64, 0, stream>>>(acc, out);
}

// Round 2
// 485.427 us; speedup vs baseline: 1.2867x; 1.2867x over previous
//
#include <hip/hip_runtime.h>
#include <hip/hip_bf16.h>

// ---------------------------------------------------------------------------
// DeepCut fused pipeline, fp32. B=4, T=4096 (64x64), D=384, K=8, CH=64, NL=4.
// Graph = 5x5 box stencil with separable D^-1/2 normalization u(i)*u(j).
// ---------------------------------------------------------------------------

#define B_ 4
#define T_ 4096
#define D_ 384
#define K_ 8
#define CH_ 64

__device__ __forceinline__ float wred(float v) {
#pragma unroll
  for (int off = 32; off > 0; off >>= 1) v += __shfl_xor(v, off);
  return v;
}

// u(i) = rsqrt(#valid offsets in [-2,2] along one axis)
__device__ __forceinline__ float uval(int i) {
  int c = (i < 2 ? i : 2) + ((63 - i) < 2 ? (63 - i) : 2) + 1;
  return rsqrtf((float)c);
}

// ---- zero the accumulator block (512 floats) ----
__global__ void k_zero(float* __restrict__ acc) {
  acc[threadIdx.x] = 0.f;
  acc[threadIdx.x + 256] = 0.f;
}

// ---- transpose ec_w1 (32,384,3,3) -> wq[q][o][d], q=ky*3+kx ----
__global__ void k_wq(const float* __restrict__ w, float* __restrict__ wq) {
  int idx = blockIdx.x * 256 + threadIdx.x;
  if (idx >= 32 * 384 * 9) return;
  int q = idx % 9;
  int rest = idx / 9;
  int d = rest % 384;
  int o = rest / 384;
  wq[((size_t)(q * 32 + o)) * 384 + d] = w[idx];
}

// ---- layer-0 GEMM: xw = [feat,pos]@W0 ; res = LN([feat,pos]@res_w + res_b) ----
__global__ __launch_bounds__(256) void k_gemm0(
    const float* __restrict__ feat, const float* __restrict__ w0,
    const float* __restrict__ resw, const float* __restrict__ resb,
    const float* __restrict__ resg, const float* __restrict__ reslb,
    float* __restrict__ xw, float* __restrict__ res) {
  __shared__ float sf[4 * 384];
  int row0 = blockIdx.x * 4;
  const float4* f4 = (const float4*)(feat + (size_t)row0 * D_);
  float4* sf4 = (float4*)sf;
  for (int i = threadIdx.x; i < 384; i += 256) sf4[i] = f4[i];
  __syncthreads();
  int r = threadIdx.x >> 6, c = threadIdx.x & 63;
  int row = row0 + r;
  int t = row & (T_ - 1);
  float px = (float)(t & 63) * (1.0f / 63.0f);
  float py = (float)(t >> 6) * (1.0f / 63.0f);
  float a1 = 0.f, a2 = 0.f;
  const float* sfr = sf + r * D_;
#pragma unroll 4
  for (int k = 0; k < D_; ++k) {
    float fv = sfr[k];
    a1 = fmaf(fv, w0[k * 64 + c], a1);
    a2 = fmaf(fv, resw[k * 64 + c], a2);
  }
  a1 += px * w0[384 * 64 + c] + py * w0[385 * 64 + c];
  a2 += px * resw[384 * 64 + c] + py * resw[385 * 64 + c] + resb[c];
  xw[(size_t)row * 64 + c] = a1;
  // LayerNorm over 64 channels (one wave = one row)
  float m = wred(a2) * (1.f / 64.f);
  float d = a2 - m;
  float v = wred(d * d) * (1.f / 64.f);
  res[(size_t)row * 64 + c] = d * rsqrtf(v + 1e-5f) * resg[c] + reslb[c];
}

// ---- generic 64->64 GEMM (no bias): Y = X@W ----
__global__ __launch_bounds__(256) void k_gemm64(const float* __restrict__ X,
                                                const float* __restrict__ W,
                                                float* __restrict__ Y) {
  __shared__ float sf[256];
  size_t base = (size_t)blockIdx.x * 256;
  sf[threadIdx.x] = X[base + threadIdx.x];
  __syncthreads();
  int r = threadIdx.x >> 6, c = threadIdx.x & 63;
  float a = 0.f;
  const float* sfr = sf + r * 64;
#pragma unroll
  for (int k = 0; k < 64; ++k) a = fmaf(sfr[k], W[k * 64 + c], a);
  Y[base + threadIdx.x] = a;
}

// ---- stencil + bias + LN + ELU + residual: xout = elu(LN(A@xw + b)) + resid ----
__global__ __launch_bounds__(256) void k_stencil(
    const float* __restrict__ xw, const float* __restrict__ bias,
    const float* __restrict__ lng, const float* __restrict__ lnb,
    const float* __restrict__ resid, float* __restrict__ xout) {
  int r = threadIdx.x >> 6, c = threadIdx.x & 63;
  int row = blockIdx.x * 4 + r;
  int b = row >> 12, t = row & (T_ - 1);
  int i = t >> 6, j = t & 63;
  float ui = uval(i), uj = uval(j);
  float s = 0.f;
#pragma unroll
  for (int di = -2; di <= 2; ++di) {
    int ii = i + di;
    if (ii < 0 || ii > 63) continue;
    float wi = uval(ii);
#pragma unroll
    for (int dj = -2; dj <= 2; ++dj) {
      int jj = j + dj;
      if (jj < 0 || jj > 63) continue;
      s = fmaf(wi * uval(jj), xw[((size_t)((b << 12) + (ii << 6) + jj)) * 64 + c], s);
    }
  }
  float h = ui * uj * s + bias[c];
  float m = wred(h) * (1.f / 64.f);
  float d = h - m;
  float v = wred(d * d) * (1.f / 64.f);
  float n = d * rsqrtf(v + 1e-5f) * lng[c] + lnb[c];
  float e = n > 0.f ? n : (expf(n) - 1.f);
  xout[(size_t)row * 64 + c] = e + resid[(size_t)row * 64 + c];
}

// ---- MLP head: h1 = elu(LN(x@w1+b1)); S = softmax(h1@w2+b2) ----
__global__ __launch_bounds__(256) void k_mlp(
    const float* __restrict__ X, const float* __restrict__ w1,
    const float* __restrict__ b1, const float* __restrict__ lng,
    const float* __restrict__ lnb, const float* __restrict__ w2,
    const float* __restrict__ b2, float* __restrict__ S) {
  int r = threadIdx.x >> 6, lane = threadIdx.x & 63;
  size_t row = (size_t)blockIdx.x * 4 + r;
  float xv = X[row * 64 + lane];
  float a = b1[lane];
#pragma unroll
  for (int k = 0; k < 64; ++k) {
    float xk = __shfl(xv, k);
    a = fmaf(xk, w1[k * 64 + lane], a);
  }
  float m = wred(a) * (1.f / 64.f);
  float d = a - m;
  float v = wred(d * d) * (1.f / 64.f);
  float h = d * rsqrtf(v + 1e-5f) * lng[lane] + lnb[lane];
  h = h > 0.f ? h : (expf(h) - 1.f);
  float lg0 = wred(h * w2[lane * 8 + 0]) + b2[0];
  float lg1 = wred(h * w2[lane * 8 + 1]) + b2[1];
  float lg2 = wred(h * w2[lane * 8 + 2]) + b2[2];
  float lg3 = wred(h * w2[lane * 8 + 3]) + b2[3];
  float lg4 = wred(h * w2[lane * 8 + 4]) + b2[4];
  float lg5 = wred(h * w2[lane * 8 + 5]) + b2[5];
  float lg6 = wred(h * w2[lane * 8 + 6]) + b2[6];
  float lg7 = wred(h * w2[lane * 8 + 7]) + b2[7];
  float mx = fmaxf(fmaxf(fmaxf(lg0, lg1), fmaxf(lg2, lg3)),
                   fmaxf(fmaxf(lg4, lg5), fmaxf(lg6, lg7)));
  lg0 = expf(lg0 - mx); lg1 = expf(lg1 - mx); lg2 = expf(lg2 - mx);
  lg3 = expf(lg3 - mx); lg4 = expf(lg4 - mx); lg5 = expf(lg5 - mx);
  lg6 = expf(lg6 - mx); lg7 = expf(lg7 - mx);
  float inv = 1.f / (lg0 + lg1 + lg2 + lg3 + lg4 + lg5 + lg6 + lg7);
  if (lane < 8) {
    float val = lane == 0 ? lg0 : lane == 1 ? lg1 : lane == 2 ? lg2 :
                lane == 3 ? lg3 : lane == 4 ? lg4 : lane == 5 ? lg5 :
                lane == 6 ? lg6 : lg7;
    S[row * 8 + lane] = val * inv;
  }
}

// ---- transpose S (B,T,K) -> Sp (B,K,T) ----
__global__ void k_transS(const float* __restrict__ S, float* __restrict__ Sp) {
  int idx = blockIdx.x * 256 + threadIdx.x;  // (b*8+k)*4096 + t
  int t = idx & (T_ - 1);
  int bk = idx >> 12;
  int k = bk & 7, b = bk >> 3;
  Sp[idx] = S[((size_t)((b << 12) + t)) * 8 + k];
}

// ---- normalized-cut num/den: AS = A@S ; num=S.AS ; den=S^2*degA ----
__global__ __launch_bounds__(256) void k_cut(const float* __restrict__ S,
                                             float* __restrict__ acc) {
  int k = threadIdx.x & 7;
  int tl = threadIdx.x >> 3;
  int gid = blockIdx.x * 32 + tl;
  int b = gid >> 12, t = gid & (T_ - 1);
  int i = t >> 6, j = t & 63;
  float ui = uval(i), uj = uval(j);
  float as = 0.f, sui = 0.f, suj = 0.f;
#pragma unroll
  for (int di = -2; di <= 2; ++di) {
    int ii = i + di;
    if (ii < 0 || ii > 63) continue;
    float wi = uval(ii);
    sui += wi;
#pragma unroll
    for (int dj = -2; dj <= 2; ++dj) {
      int jj = j + dj;
      if (jj < 0 || jj > 63) continue;
      as = fmaf(wi * uval(jj), S[((size_t)((b << 12) + (ii << 6) + jj)) * 8 + k], as);
    }
  }
#pragma unroll
  for (int dj = -2; dj <= 2; ++dj) {
    int jj = j + dj;
    if (jj >= 0 && jj <= 63) suj += uval(jj);
  }
  as *= ui * uj;
  float sv = S[(size_t)gid * 8 + k];
  float degA = ui * uj * sui * suj;
  float numv = wred(sv * as);
  float denv = wred(sv * sv * degA);
  __shared__ float lds[8];
  int wid = threadIdx.x >> 6, lane = threadIdx.x & 63;
  if (lane == 0) { lds[wid * 2] = numv; lds[wid * 2 + 1] = denv; }
  __syncthreads();
  if (threadIdx.x == 0) {
    atomicAdd(&acc[0 + b], lds[0] + lds[2] + lds[4] + lds[6]);
    atomicAdd(&acc[4 + b], lds[1] + lds[3] + lds[5] + lds[7]);
  }
}

// ---- SS[b,k,l] = sum_t S[t,k]S[t,l] ----
__global__ __launch_bounds__(256) void k_SS(const float* __restrict__ S,
                                            float* __restrict__ acc) {
  int bk = blockIdx.x;      // 32 blocks: b*8 + chunk
  int b = bk >> 3, chunk = bk & 7;
  int wid = threadIdx.x >> 6, lane = threadIdx.x & 63;
  int kk = lane >> 3, ll = lane & 7;
  int t0 = chunk * 512 + wid * 128;
  float a = 0.f;
  const float* Sb = S + ((size_t)b << 12) * 8;
  for (int it = 0; it < 128; ++it) {
    const float* sr = Sb + (size_t)(t0 + it) * 8;
    a = fmaf(sr[kk], sr[ll], a);
  }
  __shared__ float lds[256];
  lds[threadIdx.x] = a;
  __syncthreads();
  if (threadIdx.x < 64) {
    float s = lds[threadIdx.x] + lds[threadIdx.x + 64] + lds[threadIdx.x + 128] +
              lds[threadIdx.x + 192];
    atomicAdd(&acc[80 + b * 64 + threadIdx.x], s);
  }
}

// ---- spatial smoothness: per (b,k) plane, 2x depthwise conv3x3 + per-plane GN ----
__global__ __launch_bounds__(256) void k_sm(
    const float* __restrict__ Sp, const float* __restrict__ w1,
    const float* __restrict__ b1, const float* __restrict__ g1,
    const float* __restrict__ bb1, const float* __restrict__ w2,
    const float* __restrict__ b2, const float* __restrict__ g2,
    const float* __restrict__ bb2, float* __restrict__ acc) {
  __shared__ float p0[4096];
  __shared__ float p1[4096];
  __shared__ float red[8];
  int bk = blockIdx.x, b = bk >> 3, k = bk & 7;
  const float4* src = (const float4*)(Sp + (size_t)bk * 4096);
  float4* d0 = (float4*)p0;
  for (int i = threadIdx.x; i < 1024; i += 256) d0[i] = src[i];
  float W1[9], W2[9];
#pragma unroll
  for (int q = 0; q < 9; ++q) { W1[q] = w1[k * 9 + q]; W2[q] = w2[k * 9 + q]; }
  __syncthreads();
  int wid = threadIdx.x >> 6, lane = threadIdx.x & 63;
  float y[16];
  float s1 = 0.f, s2 = 0.f;
#pragma unroll
  for (int v = 0; v < 16; ++v) {
    int p = v * 256 + threadIdx.x;
    int i = p >> 6, j = p & 63;
    float a = b1[k];
#pragma unroll
    for (int dy = 0; dy < 3; ++dy) {
      int ii = i + dy - 1;
      if (ii < 0 || ii > 63) continue;
#pragma unroll
      for (int dx = 0; dx < 3; ++dx) {
        int jj = j + dx - 1;
        if (jj < 0 || jj > 63) continue;
        a = fmaf(W1[dy * 3 + dx], p0[(ii << 6) + jj], a);
      }
    }
    y[v] = a;
    s1 += a;
    s2 = fmaf(a, a, s2);
  }
  s1 = wred(s1); s2 = wred(s2);
  if (lane == 0) { red[wid * 2] = s1; red[wid * 2 + 1] = s2; }
  __syncthreads();
  float mean = (red[0] + red[2] + red[4] + red[6]) * (1.f / 4096.f);
  float var = (red[1] + red[3] + red[5] + red[7]) * (1.f / 4096.f) - mean * mean;
  float inv = rsqrtf(var + 1e-5f) * g1[k];
  float sh = bb1[k];
  __syncthreads();
#pragma unroll
  for (int v = 0; v < 16; ++v) {
    int p = v * 256 + threadIdx.x;
    p1[p] = fmaxf((y[v] - mean) * inv + sh, 0.f);
  }
  __syncthreads();
  s1 = 0.f; s2 = 0.f;
#pragma unroll
  for (int v = 0; v < 16; ++v) {
    int p = v * 256 + threadIdx.x;
    int i = p >> 6, j = p & 63;
    float a = b2[k];
#pragma unroll
    for (int dy = 0; dy < 3; ++dy) {
      int ii = i + dy - 1;
      if (ii < 0 || ii > 63) continue;
#pragma unroll
      for (int dx = 0; dx < 3; ++dx) {
        int jj = j + dx - 1;
        if (jj < 0 || jj > 63) continue;
        a = fmaf(W2[dy * 3 + dx], p1[(ii << 6) + jj], a);
      }
    }
    y[v] = a;
    s1 += a;
    s2 = fmaf(a, a, s2);
  }
  s1 = wred(s1); s2 = wred(s2);
  if (lane == 0) { red[wid * 2] = s1; red[wid * 2 + 1] = s2; }
  __syncthreads();
  float mean2 = (red[0] + red[2] + red[4] + red[6]) * (1.f / 4096.f);
  float var2 = (red[1] + red[3] + red[5] + red[7]) * (1.f / 4096.f) - mean2 * mean2;
  float inv2 = rsqrtf(var2 + 1e-5f) * g2[k];
  float sh2 = bb2[k];
  float sd = 0.f;
#pragma unroll
  for (int v = 0; v < 16; ++v) {
    int p = v * 256 + threadIdx.x;
    float sm = (y[v] - mean2) * inv2 + sh2;
    float dd = sm - p0[p];
    sd = fmaf(dd, dd, sd);
  }
  sd = wred(sd);
  __syncthreads();
  if (lane == 0) red[wid] = sd;
  __syncthreads();
  if (threadIdx.x == 0)
    atomicAdd(&acc[8 + b], (red[0] + red[1] + red[2] + red[3]) * (1.f / 32768.f));
}

// ---- edge conv, register-tiled LDS GEMM ----
// block = one image row (64 px) x 32 channels; thread = 8 px x 1 ch.
// K-chunked: Kc=32; stage 3 input rows + all 9 weight taps in LDS.
#define KC_ 32
__global__ __launch_bounds__(256) void k_ecconv(
    const float* __restrict__ feat, const float* __restrict__ wq,
    const float* __restrict__ b1, float* __restrict__ eraw,
    float* __restrict__ acc) {
  __shared__ float4 Af[3][66][9];   // [row][px+1][kquad], 36-float stride (pad)
  __shared__ float4 Wf[9][32][9];   // [q][o][kquad]
  __shared__ float sr1[4][32], sr2[4][32];
  int blk = blockIdx.x;
  int b = blk >> 6, i = blk & 63;
  int o = threadIdx.x & 31, pg = threadIdx.x >> 5;
  // zero px halo columns once (never rewritten)
  if (threadIdx.x < 48) {
    int kk = threadIdx.x & 7, side = (threadIdx.x >> 3) & 1, r = threadIdx.x >> 4;
    Af[r][side * 65][kk] = make_float4(0.f, 0.f, 0.f, 0.f);
  }
  float accv[8];
#pragma unroll
  for (int m = 0; m < 8; ++m) accv[m] = 0.f;
  for (int c = 0; c < D_ / KC_; ++c) {
    __syncthreads();
    // stage A: 3 rows x 64 px x 8 kquads
    for (int l = threadIdx.x; l < 1536; l += 256) {
      int kk = l & 7, px = (l >> 3) & 63, r = l >> 9;
      int ii = i + r - 1;
      float4 v = make_float4(0.f, 0.f, 0.f, 0.f);
      if (ii >= 0 && ii < 64)
        v = ((const float4*)(feat +
              ((size_t)((b << 12) + (ii << 6) + px)) * D_ + c * KC_))[kk];
      Af[r][px + 1][kk] = v;
    }
    // stage W: 9 q x 32 o x 8 kquads
    for (int l = threadIdx.x; l < 2304; l += 256) {
      int kk = l & 7, oo = (l >> 3) & 31, q = l >> 8;
      Wf[q][oo][kk] =
          ((const float4*)(wq + ((size_t)(q * 32 + oo)) * D_ + c * KC_))[kk];
    }
    __syncthreads();
#pragma unroll 2
    for (int kq = 0; kq < 8; ++kq) {
#pragma unroll
      for (int r = 0; r < 3; ++r) {
        float4 ar[10];
#pragma unroll
        for (int p = 0; p < 10; ++p) ar[p] = Af[r][pg * 8 + p][kq];
#pragma unroll
        for (int dx = 0; dx < 3; ++dx) {
          float4 w = Wf[r * 3 + dx][o][kq];
#pragma unroll
          for (int m = 0; m < 8; ++m) {
            float4 a4 = ar[m + dx];
            accv[m] = fmaf(a4.x, w.x, accv[m]);
            accv[m] = fmaf(a4.y, w.y, accv[m]);
            accv[m] = fmaf(a4.z, w.z, accv[m]);
            accv[m] = fmaf(a4.w, w.w, accv[m]);
          }
        }
      }
    }
  }
  // epilogue: bias, store (pixel-major), GN stats
  float bo = b1[o];
  float s1 = 0.f, s2 = 0.f;
  int base = (b << 12) + (i << 6) + pg * 8;
#pragma unroll
  for (int m = 0; m < 8; ++m) {
    float a = accv[m] + bo;
    eraw[((size_t)(base + m)) * 32 + o] = a;
    s1 += a;
    s2 = fmaf(a, a, s2);
  }
  s1 += __shfl_xor(s1, 32);
  s2 += __shfl_xor(s2, 32);
  int wid = threadIdx.x >> 6, lane = threadIdx.x & 63;
  if (lane < 32) { sr1[wid][lane] = s1; sr2[wid][lane] = s2; }
  __syncthreads();
  if (threadIdx.x < 32) {
    int oo = threadIdx.x;
    float t1 = sr1[0][oo] + sr1[1][oo] + sr1[2][oo] + sr1[3][oo];
    float t2 = sr2[0][oo] + sr2[1][oo] + sr2[2][oo] + sr2[3][oo];
    t1 += __shfl_xor(t1, 1); t1 += __shfl_xor(t1, 2);
    t2 += __shfl_xor(t2, 1); t2 += __shfl_xor(t2, 2);
    if ((oo & 3) == 0) {
      atomicAdd(&acc[16 + b * 16 + (oo >> 2) * 2], t1);
      atomicAdd(&acc[16 + b * 16 + (oo >> 2) * 2 + 1], t2);
    }
  }
}

// ---- GN + relu + 1x1 conv + sigmoid -> ew (B,T); eraw is pixel-major [b][t][32]
__global__ __launch_bounds__(256) void k_ecfinal(
    const float* __restrict__ eraw, const float* __restrict__ acc,
    const float* __restrict__ gng, const float* __restrict__ gnb,
    const float* __restrict__ w2, const float* __restrict__ b2,
    float* __restrict__ ew) {
  __shared__ float st[16];
  int idx = blockIdx.x * 256 + threadIdx.x;
  int b = idx >> 12;
  if (threadIdx.x < 16) st[threadIdx.x] = acc[16 + b * 16 + threadIdx.x];
  __syncthreads();
  float a = b2[0];
  const float4* er = (const float4*)(eraw + (size_t)idx * 32);
#pragma unroll
  for (int oq = 0; oq < 8; ++oq) {
    float mean = st[oq * 2] * (1.f / 16384.f);
    float var = st[oq * 2 + 1] * (1.f / 16384.f) - mean * mean;
    float inv = rsqrtf(var + 1e-5f);
    float4 e = er[oq];
    int o = oq * 4;
    float v0 = (e.x - mean) * inv * gng[o + 0] + gnb[o + 0];
    float v1 = (e.y - mean) * inv * gng[o + 1] + gnb[o + 1];
    float v2 = (e.z - mean) * inv * gng[o + 2] + gnb[o + 2];
    float v3 = (e.w - mean) * inv * gng[o + 3] + gnb[o + 3];
    a = fmaf(fmaxf(v0, 0.f), w2[o + 0], a);
    a = fmaf(fmaxf(v1, 0.f), w2[o + 1], a);
    a = fmaf(fmaxf(v2, 0.f), w2[o + 2], a);
    a = fmaf(fmaxf(v3, 0.f), w2[o + 3], a);
  }
  ew[idx] = 1.f / (1.f + expf(-a));
}

// ---- feature-smoothness gradient sums ----
__global__ __launch_bounds__(256) void k_fsloss(const float* __restrict__ feat,
                                                const float* __restrict__ ew,
                                                float* __restrict__ acc) {
  float sy = 0.f, sx = 0.f;
  const int N = B_ * T_ * 96;
  for (int idx = blockIdx.x * 256 + threadIdx.x; idx < N; idx += gridDim.x * 256) {
    int d4 = idx % 96;
    int rt = idx / 96;
    int t = rt & (T_ - 1);
    int i = t >> 6, j = t & 63;
    const float4* fp = (const float4*)(feat + (size_t)rt * D_) + d4;
    float4 f0 = *fp;
    if (i < 63) {
      float4 f1 = fp[64 * 96];
      float w = ew[rt + 64];
      float a = f1.x - f0.x, bq = f1.y - f0.y, c = f1.z - f0.z, d = f1.w - f0.w;
      sy += w * (a * a + bq * bq + c * c + d * d);
    }
    if (j < 63) {
      float4 f1 = fp[96];
      float w = ew[rt + 1];
      float a = f1.x - f0.x, bq = f1.y - f0.y, c = f1.z - f0.z, d = f1.w - f0.w;
      sx += w * (a * a + bq * bq + c * c + d * d);
    }
  }
  sy = wred(sy);
  sx = wred(sx);
  __shared__ float lds[8];
  int wid = threadIdx.x >> 6, lane = threadIdx.x & 63;
  if (lane == 0) { lds[wid * 2] = sy; lds[wid * 2 + 1] = sx; }
  __syncthreads();
  if (threadIdx.x == 0) {
    atomicAdd(&acc[12], lds[0] + lds[2] + lds[4] + lds[6]);
    atomicAdd(&acc[13], lds[1] + lds[3] + lds[5] + lds[7]);
  }
}

// ---- final scalar assembly ----
__global__ void k_final(const float* __restrict__ acc, float* __restrict__ out) {
  if (threadIdx.x != 0 || blockIdx.x != 0) return;
  float total = 0.f;
  for (int b = 0; b < 4; ++b) {
    const float* SSb = acc + 80 + b * 64;
    float ssq = 0.f;
    for (int v = 0; v < 64; ++v) ssq += SSb[v] * SSb[v];
    float ssn = sqrtf(ssq);
    float tgt = 1.f / (sqrtf(8.f) + 1e-6f);
    float inv = 1.f / (ssn + 1e-6f);
    float lo = 0.f;
    for (int kk = 0; kk < 8; ++kk)
      for (int ll = 0; ll < 8; ++ll) {
        float dd = SSb[kk * 8 + ll] * inv - (kk == ll ? tgt : 0.f);
        lo += dd * dd;
      }
    lo = sqrtf(lo);
    float lc = -acc[b] / (acc[4 + b] + 1e-6f);
    total += lc + lo + 0.01f * acc[8 + b];
  }
  total *= 0.25f;
  const float cnt = 4.f * 384.f * 63.f * 64.f;
  float ly = acc[12] / cnt * (1.f / 384.f);
  float lx = acc[13] / cnt * (1.f / 384.f);
  out[131072] = total + 0.09f * 0.5f * (ly + lx);
}

extern "C" void kernel_launch(void* const* d_in, const int* in_sizes, int n_in,
                              void* d_out, int out_size, void* d_ws, size_t ws_size,
                              hipStream_t stream) {
  const float* feat = (const float*)d_in[0];
  const float* gcn_w0 = (const float*)d_in[1];
  const float* gcn_b0 = (const float*)d_in[2];
  const float* gcn_w = (const float*)d_in[3];
  const float* gcn_b = (const float*)d_in[4];
  const float* ln_g = (const float*)d_in[5];
  const float* ln_b = (const float*)d_in[6];
  const float* res_w = (const float*)d_in[7];
  const float* res_b = (const float*)d_in[8];
  const float* res_ln_g = (const float*)d_in[9];
  const float* res_ln_b = (const float*)d_in[10];
  const float* mlp_w1 = (const float*)d_in[11];
  const float* mlp_b1 = (const float*)d_in[12];
  const float* mlp_ln_g = (const float*)d_in[13];
  const float* mlp_ln_b = (const float*)d_in[14];
  const float* mlp_w2 = (const float*)d_in[15];
  const float* mlp_b2 = (const float*)d_in[16];
  const float* sm_w1 = (const float*)d_in[17];
  const float* sm_b1 = (const float*)d_in[18];
  const float* sm_g1 = (const float*)d_in[19];
  const float* sm_bb1 = (const float*)d_in[20];
  const float* sm_w2 = (const float*)d_in[21];
  const float* sm_b2 = (const float*)d_in[22];
  const float* sm_g2 = (const float*)d_in[23];
  const float* sm_bb2 = (const float*)d_in[24];
  const float* ec_w1 = (const float*)d_in[25];
  const float* ec_b1 = (const float*)d_in[26];
  const float* ec_gn_g = (const float*)d_in[27];
  const float* ec_gn_b = (const float*)d_in[28];
  const float* ec_w2 = (const float*)d_in[29];
  const float* ec_b2 = (const float*)d_in[30];

  float* out = (float*)d_out;
  float* ws = (float*)d_ws;
  float* acc = ws;                       // 512 floats
  float* xw = ws + 512;                  // B*T*64
  float* xbuf = xw + 1048576;            // B*T*64
  float* resbuf = xbuf + 1048576;        // B*T*64
  float* Sp = resbuf + 1048576;          // B*K*T
  float* eraw = Sp + 131072;             // B*T*32 (pixel-major)
  float* ew = eraw + 524288;             // B*T
  float* wqb = ew + 16384;               // 110592
  float* S = out;                        // (B,T,K) straight into d_out

  k_zero<<<1, 256, 0, stream>>>(acc);
  k_wq<<<(110592 + 255) / 256, 256, 0, stream>>>(ec_w1, wqb);

  k_gemm0<<<B_ * T_ / 4, 256, 0, stream>>>(feat, gcn_w0, res_w, res_b, res_ln_g,
                                           res_ln_b, xw, resbuf);
  k_stencil<<<B_ * T_ / 4, 256, 0, stream>>>(xw, gcn_b0, ln_g, ln_b, resbuf, xbuf);
  for (int i = 1; i < 4; ++i) {
    k_gemm64<<<B_ * T_ / 4, 256, 0, stream>>>(xbuf, gcn_w + (i - 1) * 4096, xw);
    k_stencil<<<B_ * T_ / 4, 256, 0, stream>>>(xw, gcn_b + (i - 1) * 64,
                                               ln_g + i * 64, ln_b + i * 64, xbuf,
                                               xbuf);
  }
  k_mlp<<<B_ * T_ / 4, 256, 0, stream>>>(xbuf, mlp_w1, mlp_b1, mlp_ln_g, mlp_ln_b,
                                         mlp_w2, mlp_b2, S);

  k_transS<<<B_ * K_ * T_ / 256, 256, 0, stream>>>(S, Sp);
  k_cut<<<B_ * T_ / 32, 256, 0, stream>>>(S, acc);
  k_SS<<<32, 256, 0, stream>>>(S, acc);
  k_sm<<<32, 256, 0, stream>>>(Sp, sm_w1, sm_b1, sm_g1, sm_bb1, sm_w2, sm_b2, sm_g2,
                               sm_bb2, acc);

  k_ecconv<<<256, 256, 0, stream>>>(feat, wqb, ec_b1, eraw, acc);
  k_ecfinal<<<B_ * T_ / 256, 256, 0, stream>>>(eraw, acc, ec_gn_g, ec_gn_b, ec_w2,
                                               ec_b2, ew);
  k_fsloss<<<2048, 256, 0, stream>>>(feat, ew, acc);
  k_final<<<1, 64, 0, stream>>>(acc, out);
}

// Round 3
// 371.314 us; speedup vs baseline: 1.6821x; 1.3073x over previous
//
#include <hip/hip_runtime.h>
#include <hip/hip_bf16.h>

// ---------------------------------------------------------------------------
// DeepCut fused pipeline. B=4, T=4096 (64x64), D=384, K=8, CH=64, NL=4.
// Graph = 5x5 box stencil with separable D^-1/2 normalization u(i)*u(j).
// Edge-conv uses bf16 MFMA (loss-only path; S stays fp32).
// ---------------------------------------------------------------------------

#define B_ 4
#define T_ 4096
#define D_ 384
#define K_ 8
#define CH_ 64

typedef __attribute__((ext_vector_type(8))) short short8b;
typedef __attribute__((ext_vector_type(4))) float f32x4;

__device__ __forceinline__ float wred(float v) {
#pragma unroll
  for (int off = 32; off > 0; off >>= 1) v += __shfl_xor(v, off);
  return v;
}

__device__ __forceinline__ short bf16rne(float f) {
  unsigned u = __float_as_uint(f);
  unsigned r = (u + 0x7FFFu + ((u >> 16) & 1u)) >> 16;
  return (short)r;
}

// u(i) = rsqrt(#valid offsets in [-2,2] along one axis)
__device__ __forceinline__ float uval(int i) {
  int c = (i < 2 ? i : 2) + ((63 - i) < 2 ? (63 - i) : 2) + 1;
  return rsqrtf((float)c);
}

// ---- transpose ec_w1 (32,384,3,3) -> wq[q][o][d] bf16, q=ky*3+kx; zero acc ----
__global__ void k_wq(const float* __restrict__ w, short* __restrict__ wq,
                     float* __restrict__ accg) {
  if (blockIdx.x == 0) {
    accg[threadIdx.x] = 0.f;
    accg[threadIdx.x + 256] = 0.f;
  }
  int idx = blockIdx.x * 256 + threadIdx.x;
  if (idx >= 32 * 384 * 9) return;
  int q = idx % 9;
  int rest = idx / 9;
  int d = rest % 384;
  int o = rest / 384;
  wq[((size_t)(q * 32 + o)) * 384 + d] = bf16rne(w[idx]);
}

// ---- layer-0 GEMM: xw = [feat,pos]@W0 ; res = LN([feat,pos]@res_w + res_b) ----
__global__ __launch_bounds__(256) void k_gemm0(
    const float* __restrict__ feat, const float* __restrict__ w0,
    const float* __restrict__ resw, const float* __restrict__ resb,
    const float* __restrict__ resg, const float* __restrict__ reslb,
    float* __restrict__ xw, float* __restrict__ res) {
  __shared__ float sf[4 * 384];
  int row0 = blockIdx.x * 4;
  const float4* f4 = (const float4*)(feat + (size_t)row0 * D_);
  float4* sf4 = (float4*)sf;
  for (int i = threadIdx.x; i < 384; i += 256) sf4[i] = f4[i];
  __syncthreads();
  int r = threadIdx.x >> 6, c = threadIdx.x & 63;
  int row = row0 + r;
  int t = row & (T_ - 1);
  float px = (float)(t & 63) * (1.0f / 63.0f);
  float py = (float)(t >> 6) * (1.0f / 63.0f);
  float a1 = 0.f, a2 = 0.f;
  const float* sfr = sf + r * D_;
#pragma unroll 4
  for (int k = 0; k < D_; ++k) {
    float fv = sfr[k];
    a1 = fmaf(fv, w0[k * 64 + c], a1);
    a2 = fmaf(fv, resw[k * 64 + c], a2);
  }
  a1 += px * w0[384 * 64 + c] + py * w0[385 * 64 + c];
  a2 += px * resw[384 * 64 + c] + py * resw[385 * 64 + c] + resb[c];
  xw[(size_t)row * 64 + c] = a1;
  float m = wred(a2) * (1.f / 64.f);
  float d = a2 - m;
  float v = wred(d * d) * (1.f / 64.f);
  res[(size_t)row * 64 + c] = d * rsqrtf(v + 1e-5f) * resg[c] + reslb[c];
}

// ---- generic 64->64 GEMM (no bias): Y = X@W ----
__global__ __launch_bounds__(256) void k_gemm64(const float* __restrict__ X,
                                                const float* __restrict__ W,
                                                float* __restrict__ Y) {
  __shared__ float sf[256];
  size_t base = (size_t)blockIdx.x * 256;
  sf[threadIdx.x] = X[base + threadIdx.x];
  __syncthreads();
  int r = threadIdx.x >> 6, c = threadIdx.x & 63;
  float a = 0.f;
  const float* sfr = sf + r * 64;
#pragma unroll
  for (int k = 0; k < 64; ++k) a = fmaf(sfr[k], W[k * 64 + c], a);
  Y[base + threadIdx.x] = a;
}

// ---- stencil + bias + LN + ELU + residual ----
__global__ __launch_bounds__(256) void k_stencil(
    const float* __restrict__ xw, const float* __restrict__ bias,
    const float* __restrict__ lng, const float* __restrict__ lnb,
    const float* __restrict__ resid, float* __restrict__ xout) {
  int r = threadIdx.x >> 6, c = threadIdx.x & 63;
  int row = blockIdx.x * 4 + r;
  int b = row >> 12, t = row & (T_ - 1);
  int i = t >> 6, j = t & 63;
  float ui = uval(i), uj = uval(j);
  float s = 0.f;
#pragma unroll
  for (int di = -2; di <= 2; ++di) {
    int ii = i + di;
    if (ii < 0 || ii > 63) continue;
    float wi = uval(ii);
#pragma unroll
    for (int dj = -2; dj <= 2; ++dj) {
      int jj = j + dj;
      if (jj < 0 || jj > 63) continue;
      s = fmaf(wi * uval(jj), xw[((size_t)((b << 12) + (ii << 6) + jj)) * 64 + c], s);
    }
  }
  float h = ui * uj * s + bias[c];
  float m = wred(h) * (1.f / 64.f);
  float d = h - m;
  float v = wred(d * d) * (1.f / 64.f);
  float n = d * rsqrtf(v + 1e-5f) * lng[c] + lnb[c];
  float e = n > 0.f ? n : (expf(n) - 1.f);
  xout[(size_t)row * 64 + c] = e + resid[(size_t)row * 64 + c];
}

// ---- MLP head: h1 = elu(LN(x@w1+b1)); S = softmax(h1@w2+b2); also writes Sp ----
__global__ __launch_bounds__(256) void k_mlp(
    const float* __restrict__ X, const float* __restrict__ w1,
    const float* __restrict__ b1, const float* __restrict__ lng,
    const float* __restrict__ lnb, const float* __restrict__ w2,
    const float* __restrict__ b2, float* __restrict__ S, float* __restrict__ Sp) {
  int r = threadIdx.x >> 6, lane = threadIdx.x & 63;
  size_t row = (size_t)blockIdx.x * 4 + r;
  float xv = X[row * 64 + lane];
  float a = b1[lane];
#pragma unroll
  for (int k = 0; k < 64; ++k) {
    float xk = __shfl(xv, k);
    a = fmaf(xk, w1[k * 64 + lane], a);
  }
  float m = wred(a) * (1.f / 64.f);
  float d = a - m;
  float v = wred(d * d) * (1.f / 64.f);
  float h = d * rsqrtf(v + 1e-5f) * lng[lane] + lnb[lane];
  h = h > 0.f ? h : (expf(h) - 1.f);
  float lg0 = wred(h * w2[lane * 8 + 0]) + b2[0];
  float lg1 = wred(h * w2[lane * 8 + 1]) + b2[1];
  float lg2 = wred(h * w2[lane * 8 + 2]) + b2[2];
  float lg3 = wred(h * w2[lane * 8 + 3]) + b2[3];
  float lg4 = wred(h * w2[lane * 8 + 4]) + b2[4];
  float lg5 = wred(h * w2[lane * 8 + 5]) + b2[5];
  float lg6 = wred(h * w2[lane * 8 + 6]) + b2[6];
  float lg7 = wred(h * w2[lane * 8 + 7]) + b2[7];
  float mx = fmaxf(fmaxf(fmaxf(lg0, lg1), fmaxf(lg2, lg3)),
                   fmaxf(fmaxf(lg4, lg5), fmaxf(lg6, lg7)));
  lg0 = expf(lg0 - mx); lg1 = expf(lg1 - mx); lg2 = expf(lg2 - mx);
  lg3 = expf(lg3 - mx); lg4 = expf(lg4 - mx); lg5 = expf(lg5 - mx);
  lg6 = expf(lg6 - mx); lg7 = expf(lg7 - mx);
  float inv = 1.f / (lg0 + lg1 + lg2 + lg3 + lg4 + lg5 + lg6 + lg7);
  if (lane < 8) {
    float val = lane == 0 ? lg0 : lane == 1 ? lg1 : lane == 2 ? lg2 :
                lane == 3 ? lg3 : lane == 4 ? lg4 : lane == 5 ? lg5 :
                lane == 6 ? lg6 : lg7;
    val *= inv;
    int b = (int)(row >> 12), t = (int)(row & (T_ - 1));
    S[row * 8 + lane] = val;
    Sp[((size_t)((b << 3) + lane) << 12) + t] = val;
  }
}

// ---- merged normalized-cut (blocks 0..511) + SS (blocks 0..31 extra) ----
__global__ __launch_bounds__(256) void k_cutss(const float* __restrict__ S,
                                               float* __restrict__ accg) {
  {
    int k = threadIdx.x & 7;
    int tl = threadIdx.x >> 3;
    int gid = blockIdx.x * 32 + tl;
    int b = gid >> 12, t = gid & (T_ - 1);
    int i = t >> 6, j = t & 63;
    float ui = uval(i), uj = uval(j);
    float as = 0.f, sui = 0.f, suj = 0.f;
#pragma unroll
    for (int di = -2; di <= 2; ++di) {
      int ii = i + di;
      if (ii < 0 || ii > 63) continue;
      float wi = uval(ii);
      sui += wi;
#pragma unroll
      for (int dj = -2; dj <= 2; ++dj) {
        int jj = j + dj;
        if (jj < 0 || jj > 63) continue;
        as = fmaf(wi * uval(jj),
                  S[((size_t)((b << 12) + (ii << 6) + jj)) * 8 + k], as);
      }
    }
#pragma unroll
    for (int dj = -2; dj <= 2; ++dj) {
      int jj = j + dj;
      if (jj >= 0 && jj <= 63) suj += uval(jj);
    }
    as *= ui * uj;
    float sv = S[(size_t)gid * 8 + k];
    float degA = ui * uj * sui * suj;
    float numv = wred(sv * as);
    float denv = wred(sv * sv * degA);
    __shared__ float lds[8];
    int wid = threadIdx.x >> 6, lane = threadIdx.x & 63;
    if (lane == 0) { lds[wid * 2] = numv; lds[wid * 2 + 1] = denv; }
    __syncthreads();
    if (threadIdx.x == 0) {
      atomicAdd(&accg[0 + b], lds[0] + lds[2] + lds[4] + lds[6]);
      atomicAdd(&accg[4 + b], lds[1] + lds[3] + lds[5] + lds[7]);
    }
  }
  if (blockIdx.x < 32) {
    int b = blockIdx.x >> 3, chunk = blockIdx.x & 7;
    int wid = threadIdx.x >> 6, lane = threadIdx.x & 63;
    int kk = lane >> 3, ll = lane & 7;
    int t0 = chunk * 512 + wid * 128;
    float a = 0.f;
    const float* Sb = S + ((size_t)b << 12) * 8;
    for (int it = 0; it < 128; ++it) {
      const float* sr = Sb + (size_t)(t0 + it) * 8;
      a = fmaf(sr[kk], sr[ll], a);
    }
    __shared__ float lds2[256];
    lds2[threadIdx.x] = a;
    __syncthreads();
    if (threadIdx.x < 64) {
      float s = lds2[threadIdx.x] + lds2[threadIdx.x + 64] +
                lds2[threadIdx.x + 128] + lds2[threadIdx.x + 192];
      atomicAdd(&accg[80 + b * 64 + threadIdx.x], s);
    }
  }
}

// ---- spatial smoothness: per (b,k) plane, 2x depthwise conv3x3 + per-plane GN ----
__global__ __launch_bounds__(256) void k_sm(
    const float* __restrict__ Sp, const float* __restrict__ w1,
    const float* __restrict__ b1, const float* __restrict__ g1,
    const float* __restrict__ bb1, const float* __restrict__ w2,
    const float* __restrict__ b2, const float* __restrict__ g2,
    const float* __restrict__ bb2, float* __restrict__ accg) {
  __shared__ float p0[4096];
  __shared__ float p1[4096];
  __shared__ float red[8];
  int bk = blockIdx.x, b = bk >> 3, k = bk & 7;
  const float4* src = (const float4*)(Sp + (size_t)bk * 4096);
  float4* d0 = (float4*)p0;
  for (int i = threadIdx.x; i < 1024; i += 256) d0[i] = src[i];
  float W1[9], W2[9];
#pragma unroll
  for (int q = 0; q < 9; ++q) { W1[q] = w1[k * 9 + q]; W2[q] = w2[k * 9 + q]; }
  __syncthreads();
  int wid = threadIdx.x >> 6, lane = threadIdx.x & 63;
  float y[16];
  float s1 = 0.f, s2 = 0.f;
#pragma unroll
  for (int v = 0; v < 16; ++v) {
    int p = v * 256 + threadIdx.x;
    int i = p >> 6, j = p & 63;
    float a = b1[k];
#pragma unroll
    for (int dy = 0; dy < 3; ++dy) {
      int ii = i + dy - 1;
      if (ii < 0 || ii > 63) continue;
#pragma unroll
      for (int dx = 0; dx < 3; ++dx) {
        int jj = j + dx - 1;
        if (jj < 0 || jj > 63) continue;
        a = fmaf(W1[dy * 3 + dx], p0[(ii << 6) + jj], a);
      }
    }
    y[v] = a;
    s1 += a;
    s2 = fmaf(a, a, s2);
  }
  s1 = wred(s1); s2 = wred(s2);
  if (lane == 0) { red[wid * 2] = s1; red[wid * 2 + 1] = s2; }
  __syncthreads();
  float mean = (red[0] + red[2] + red[4] + red[6]) * (1.f / 4096.f);
  float var = (red[1] + red[3] + red[5] + red[7]) * (1.f / 4096.f) - mean * mean;
  float inv = rsqrtf(var + 1e-5f) * g1[k];
  float sh = bb1[k];
  __syncthreads();
#pragma unroll
  for (int v = 0; v < 16; ++v) {
    int p = v * 256 + threadIdx.x;
    p1[p] = fmaxf((y[v] - mean) * inv + sh, 0.f);
  }
  __syncthreads();
  s1 = 0.f; s2 = 0.f;
#pragma unroll
  for (int v = 0; v < 16; ++v) {
    int p = v * 256 + threadIdx.x;
    int i = p >> 6, j = p & 63;
    float a = b2[k];
#pragma unroll
    for (int dy = 0; dy < 3; ++dy) {
      int ii = i + dy - 1;
      if (ii < 0 || ii > 63) continue;
#pragma unroll
      for (int dx = 0; dx < 3; ++dx) {
        int jj = j + dx - 1;
        if (jj < 0 || jj > 63) continue;
        a = fmaf(W2[dy * 3 + dx], p1[(ii << 6) + jj], a);
      }
    }
    y[v] = a;
    s1 += a;
    s2 = fmaf(a, a, s2);
  }
  s1 = wred(s1); s2 = wred(s2);
  if (lane == 0) { red[wid * 2] = s1; red[wid * 2 + 1] = s2; }
  __syncthreads();
  float mean2 = (red[0] + red[2] + red[4] + red[6]) * (1.f / 4096.f);
  float var2 = (red[1] + red[3] + red[5] + red[7]) * (1.f / 4096.f) - mean2 * mean2;
  float inv2 = rsqrtf(var2 + 1e-5f) * g2[k];
  float sh2 = bb2[k];
  float sd = 0.f;
#pragma unroll
  for (int v = 0; v < 16; ++v) {
    int p = v * 256 + threadIdx.x;
    float sm = (y[v] - mean2) * inv2 + sh2;
    float dd = sm - p0[p];
    sd = fmaf(dd, dd, sd);
  }
  sd = wred(sd);
  __syncthreads();
  if (lane == 0) red[wid] = sd;
  __syncthreads();
  if (threadIdx.x == 0)
    atomicAdd(&accg[8 + b], (red[0] + red[1] + red[2] + red[3]) * (1.f / 32768.f));
}

// ---- edge conv via bf16 MFMA: block = image row, 64px x 32ch, K'=9*384 ----
__global__ __launch_bounds__(256) void k_ecconv(
    const float* __restrict__ feat, const short* __restrict__ wq,
    const float* __restrict__ bias1, float* __restrict__ eraw,
    float* __restrict__ accg) {
  __shared__ __align__(16) short Abuf[3 * 67 * 32];  // [r][px slot 0..66][32d]
  __shared__ __align__(16) short Wbuf[9 * 32 * 32];  // [q][o][32d]
  __shared__ float sW1[4][32], sW2[4][32];
  int blk = blockIdx.x;
  int b = blk >> 6, i = blk & 63;
  int tid = threadIdx.x;
  int wid = tid >> 6, lane = tid & 63;
  int m = lane & 15, kg = lane >> 4;
  // zero halo slots (px 0, 65, 66 for each r) once
  if (tid < 36) {
    int zkg = tid & 3, sl = (tid >> 2) % 3, r = tid / 12;
    int slot = sl == 0 ? 0 : (sl == 1 ? 65 : 66);
    *(short8b*)&Abuf[(r * 67 + slot) * 32 + zkg * 8] = (short8b)0;
  }
  f32x4 acc0 = {0.f, 0.f, 0.f, 0.f};
  f32x4 acc1 = {0.f, 0.f, 0.f, 0.f};
  int abase = (wid * 16 + m) * 32 + kg * 8;  // + (r*67+dx)*32 per q
  int bbase = m * 32 + kg * 8;               // + q*1024 (+512 for nt=1)
  for (int c = 0; c < 12; ++c) {
    __syncthreads();
    // stage A: 3 rows x 64 px x 32 d (fp32 -> bf16)
#pragma unroll
    for (int s = 0; s < 3; ++s) {
      int cid = tid + (s << 8);
      int akg = cid & 3, px = (cid >> 2) & 63, r = cid >> 8;
      int ii = i + r - 1;
      short8b v = (short8b)0;
      if (ii >= 0 && ii < 64) {
        const float* src =
            feat + ((size_t)((b << 12) + (ii << 6) + px)) * D_ + c * 32 + akg * 8;
        float4 f0 = *(const float4*)src;
        float4 f1 = *(const float4*)(src + 4);
        v[0] = bf16rne(f0.x); v[1] = bf16rne(f0.y);
        v[2] = bf16rne(f0.z); v[3] = bf16rne(f0.w);
        v[4] = bf16rne(f1.x); v[5] = bf16rne(f1.y);
        v[6] = bf16rne(f1.z); v[7] = bf16rne(f1.w);
      }
      *(short8b*)&Abuf[(r * 67 + px + 1) * 32 + akg * 8] = v;
    }
    // stage W: 9 q x 32 o x 32 d (already bf16)
    for (int l = tid; l < 1152; l += 256) {
      int wkg = l & 3, oo = (l >> 2) & 31, q = l >> 7;
      short8b wv =
          *(const short8b*)(wq + ((size_t)(q * 32 + oo)) * D_ + c * 32 + wkg * 8);
      *(short8b*)&Wbuf[(q * 32 + oo) * 32 + wkg * 8] = wv;
    }
    __syncthreads();
#pragma unroll
    for (int q = 0; q < 9; ++q) {
      short8b av = *(const short8b*)&Abuf[abase + ((q / 3) * 67 + (q % 3)) * 32];
      short8b bv0 = *(const short8b*)&Wbuf[bbase + q * 1024];
      short8b bv1 = *(const short8b*)&Wbuf[bbase + q * 1024 + 512];
      acc0 = __builtin_amdgcn_mfma_f32_16x16x32_bf16(av, bv0, acc0, 0, 0, 0);
      acc1 = __builtin_amdgcn_mfma_f32_16x16x32_bf16(av, bv1, acc1, 0, 0, 0);
    }
  }
  // epilogue: bias, store pixel-major, GN stats
  int o0 = m, o1 = 16 + m;
  float bs0 = bias1[o0], bs1 = bias1[o1];
  float s1a = 0.f, s2a = 0.f, s1b = 0.f, s2b = 0.f;
  int jbase = wid * 16 + kg * 4;
#pragma unroll
  for (int rg = 0; rg < 4; ++rg) {
    float v0 = acc0[rg] + bs0;
    float v1 = acc1[rg] + bs1;
    int j = jbase + rg;
    size_t px = ((size_t)((b << 12) + (i << 6) + j)) * 32;
    eraw[px + o0] = v0;
    eraw[px + o1] = v1;
    s1a += v0; s2a = fmaf(v0, v0, s2a);
    s1b += v1; s2b = fmaf(v1, v1, s2b);
  }
  s1a += __shfl_xor(s1a, 16); s1a += __shfl_xor(s1a, 32);
  s2a += __shfl_xor(s2a, 16); s2a += __shfl_xor(s2a, 32);
  s1b += __shfl_xor(s1b, 16); s1b += __shfl_xor(s1b, 32);
  s2b += __shfl_xor(s2b, 16); s2b += __shfl_xor(s2b, 32);
  if (lane < 16) {
    sW1[wid][lane] = s1a; sW2[wid][lane] = s2a;
    sW1[wid][lane + 16] = s1b; sW2[wid][lane + 16] = s2b;
  }
  __syncthreads();
  if (tid < 32) {
    float t1 = sW1[0][tid] + sW1[1][tid] + sW1[2][tid] + sW1[3][tid];
    float t2 = sW2[0][tid] + sW2[1][tid] + sW2[2][tid] + sW2[3][tid];
    t1 += __shfl_xor(t1, 1); t1 += __shfl_xor(t1, 2);
    t2 += __shfl_xor(t2, 1); t2 += __shfl_xor(t2, 2);
    if ((tid & 3) == 0) {
      atomicAdd(&accg[16 + b * 16 + (tid >> 2) * 2], t1);
      atomicAdd(&accg[16 + b * 16 + (tid >> 2) * 2 + 1], t2);
    }
  }
}

// ---- GN + relu + 1x1 conv + sigmoid -> ew (B,T); eraw pixel-major [b][t][32]
__global__ __launch_bounds__(256) void k_ecfinal(
    const float* __restrict__ eraw, const float* __restrict__ accg,
    const float* __restrict__ gng, const float* __restrict__ gnb,
    const float* __restrict__ w2, const float* __restrict__ b2,
    float* __restrict__ ew) {
  __shared__ float st[16];
  int idx = blockIdx.x * 256 + threadIdx.x;
  int b = idx >> 12;
  if (threadIdx.x < 16) st[threadIdx.x] = accg[16 + b * 16 + threadIdx.x];
  __syncthreads();
  float a = b2[0];
  const float4* er = (const float4*)(eraw + (size_t)idx * 32);
#pragma unroll
  for (int oq = 0; oq < 8; ++oq) {
    float mean = st[oq * 2] * (1.f / 16384.f);
    float var = st[oq * 2 + 1] * (1.f / 16384.f) - mean * mean;
    float inv = rsqrtf(var + 1e-5f);
    float4 e = er[oq];
    int o = oq * 4;
    float v0 = (e.x - mean) * inv * gng[o + 0] + gnb[o + 0];
    float v1 = (e.y - mean) * inv * gng[o + 1] + gnb[o + 1];
    float v2 = (e.z - mean) * inv * gng[o + 2] + gnb[o + 2];
    float v3 = (e.w - mean) * inv * gng[o + 3] + gnb[o + 3];
    a = fmaf(fmaxf(v0, 0.f), w2[o + 0], a);
    a = fmaf(fmaxf(v1, 0.f), w2[o + 1], a);
    a = fmaf(fmaxf(v2, 0.f), w2[o + 2], a);
    a = fmaf(fmaxf(v3, 0.f), w2[o + 3], a);
  }
  ew[idx] = 1.f / (1.f + expf(-a));
}

// ---- feature-smoothness gradient sums ----
__global__ __launch_bounds__(256) void k_fsloss(const float* __restrict__ feat,
                                                const float* __restrict__ ew,
                                                float* __restrict__ accg) {
  float sy = 0.f, sx = 0.f;
  const int N = B_ * T_ * 96;
  for (int idx = blockIdx.x * 256 + threadIdx.x; idx < N; idx += gridDim.x * 256) {
    int d4 = idx % 96;
    int rt = idx / 96;
    int t = rt & (T_ - 1);
    int i = t >> 6, j = t & 63;
    const float4* fp = (const float4*)(feat + (size_t)rt * D_) + d4;
    float4 f0 = *fp;
    if (i < 63) {
      float4 f1 = fp[64 * 96];
      float w = ew[rt + 64];
      float a = f1.x - f0.x, bq = f1.y - f0.y, c = f1.z - f0.z, d = f1.w - f0.w;
      sy += w * (a * a + bq * bq + c * c + d * d);
    }
    if (j < 63) {
      float4 f1 = fp[96];
      float w = ew[rt + 1];
      float a = f1.x - f0.x, bq = f1.y - f0.y, c = f1.z - f0.z, d = f1.w - f0.w;
      sx += w * (a * a + bq * bq + c * c + d * d);
    }
  }
  sy = wred(sy);
  sx = wred(sx);
  __shared__ float lds[8];
  int wid = threadIdx.x >> 6, lane = threadIdx.x & 63;
  if (lane == 0) { lds[wid * 2] = sy; lds[wid * 2 + 1] = sx; }
  __syncthreads();
  if (threadIdx.x == 0) {
    atomicAdd(&accg[12], lds[0] + lds[2] + lds[4] + lds[6]);
    atomicAdd(&accg[13], lds[1] + lds[3] + lds[5] + lds[7]);
  }
}

// ---- final scalar assembly ----
__global__ void k_final(const float* __restrict__ accg, float* __restrict__ out) {
  if (threadIdx.x != 0 || blockIdx.x != 0) return;
  float total = 0.f;
  for (int b = 0; b < 4; ++b) {
    const float* SSb = accg + 80 + b * 64;
    float ssq = 0.f;
    for (int v = 0; v < 64; ++v) ssq += SSb[v] * SSb[v];
    float ssn = sqrtf(ssq);
    float tgt = 1.f / (sqrtf(8.f) + 1e-6f);
    float inv = 1.f / (ssn + 1e-6f);
    float lo = 0.f;
    for (int kk = 0; kk < 8; ++kk)
      for (int ll = 0; ll < 8; ++ll) {
        float dd = SSb[kk * 8 + ll] * inv - (kk == ll ? tgt : 0.f);
        lo += dd * dd;
      }
    lo = sqrtf(lo);
    float lc = -accg[b] / (accg[4 + b] + 1e-6f);
    total += lc + lo + 0.01f * accg[8 + b];
  }
  total *= 0.25f;
  const float cnt = 4.f * 384.f * 63.f * 64.f;
  float ly = accg[12] / cnt * (1.f / 384.f);
  float lx = accg[13] / cnt * (1.f / 384.f);
  out[131072] = total + 0.09f * 0.5f * (ly + lx);
}

extern "C" void kernel_launch(void* const* d_in, const int* in_sizes, int n_in,
                              void* d_out, int out_size, void* d_ws, size_t ws_size,
                              hipStream_t stream) {
  const float* feat = (const float*)d_in[0];
  const float* gcn_w0 = (const float*)d_in[1];
  const float* gcn_b0 = (const float*)d_in[2];
  const float* gcn_w = (const float*)d_in[3];
  const float* gcn_b = (const float*)d_in[4];
  const float* ln_g = (const float*)d_in[5];
  const float* ln_b = (const float*)d_in[6];
  const float* res_w = (const float*)d_in[7];
  const float* res_b = (const float*)d_in[8];
  const float* res_ln_g = (const float*)d_in[9];
  const float* res_ln_b = (const float*)d_in[10];
  const float* mlp_w1 = (const float*)d_in[11];
  const float* mlp_b1 = (const float*)d_in[12];
  const float* mlp_ln_g = (const float*)d_in[13];
  const float* mlp_ln_b = (const float*)d_in[14];
  const float* mlp_w2 = (const float*)d_in[15];
  const float* mlp_b2 = (const float*)d_in[16];
  const float* sm_w1 = (const float*)d_in[17];
  const float* sm_b1 = (const float*)d_in[18];
  const float* sm_g1 = (const float*)d_in[19];
  const float* sm_bb1 = (const float*)d_in[20];
  const float* sm_w2 = (const float*)d_in[21];
  const float* sm_b2 = (const float*)d_in[22];
  const float* sm_g2 = (const float*)d_in[23];
  const float* sm_bb2 = (const float*)d_in[24];
  const float* ec_w1 = (const float*)d_in[25];
  const float* ec_b1 = (const float*)d_in[26];
  const float* ec_gn_g = (const float*)d_in[27];
  const float* ec_gn_b = (const float*)d_in[28];
  const float* ec_w2 = (const float*)d_in[29];
  const float* ec_b2 = (const float*)d_in[30];

  float* out = (float*)d_out;
  float* ws = (float*)d_ws;
  float* acc = ws;                       // 512 floats
  float* xw = ws + 512;                  // B*T*64
  float* xbuf = xw + 1048576;            // B*T*64
  float* resbuf = xbuf + 1048576;        // B*T*64
  float* Sp = resbuf + 1048576;          // B*K*T
  float* eraw = Sp + 131072;             // B*T*32 (pixel-major)
  float* ew = eraw + 524288;             // B*T
  short* wqb = (short*)(ew + 16384);     // 110592 shorts (bf16)
  float* S = out;                        // (B,T,K) straight into d_out

  k_wq<<<(110592 + 255) / 256, 256, 0, stream>>>(ec_w1, wqb, acc);

  k_gemm0<<<B_ * T_ / 4, 256, 0, stream>>>(feat, gcn_w0, res_w, res_b, res_ln_g,
                                           res_ln_b, xw, resbuf);
  k_stencil<<<B_ * T_ / 4, 256, 0, stream>>>(xw, gcn_b0, ln_g, ln_b, resbuf, xbuf);
  for (int i = 1; i < 4; ++i) {
    k_gemm64<<<B_ * T_ / 4, 256, 0, stream>>>(xbuf, gcn_w + (i - 1) * 4096, xw);
    k_stencil<<<B_ * T_ / 4, 256, 0, stream>>>(xw, gcn_b + (i - 1) * 64,
                                               ln_g + i * 64, ln_b + i * 64, xbuf,
                                               xbuf);
  }
  k_mlp<<<B_ * T_ / 4, 256, 0, stream>>>(xbuf, mlp_w1, mlp_b1, mlp_ln_g, mlp_ln_b,
                                         mlp_w2, mlp_b2, S, Sp);

  k_cutss<<<B_ * T_ / 32, 256, 0, stream>>>(S, acc);
  k_sm<<<32, 256, 0, stream>>>(Sp, sm_w1, sm_b1, sm_g1, sm_bb1, sm_w2, sm_b2, sm_g2,
                               sm_bb2, acc);

  k_ecconv<<<256, 256, 0, stream>>>(feat, wqb, ec_b1, eraw, acc);
  k_ecfinal<<<B_ * T_ / 256, 256, 0, stream>>>(eraw, acc, ec_gn_g, ec_gn_b, ec_w2,
                                               ec_b2, ew);
  k_fsloss<<<2048, 256, 0, stream>>>(feat, ew, acc);
  k_final<<<1, 64, 0, stream>>>(acc, out);
}